// Round 3
// baseline (5478.748 us; speedup 1.0000x reference)
//
#include <hip/hip_runtime.h>

// EquivariantProductBasisBlock (MACE symmetric contraction, corr=3) + o3.Linear
// N=10000 nodes, C=128 channels, L=9 (lmax=2), E=5 elements, fp32 throughout.
//
// R3 changes vs R2:
//  - contract_kernel was scratch-bound: `unroll 1` on u/v made x[i][v]/x[i][u]
//    runtime-indexed -> x demoted to scratch (VGPR=32, FETCH 850 MB). Now u,v
//    are FULLY unrolled (all x indices compile-time); only dd stays rolled.
//  - single-block sort replaced by 3 parallel kernels (count / prefix /
//    wave-aggregated scatter).

#define CCH 128
#define LDIM 9
#define NE 5
// table layout per (e,c): T3[dd][81 rows][12 padded] | T2[dd][81] | T1[dd][9]
#define T3ROW 12
#define T2_OFF 3888           // 4*81*12
#define T1_OFF 4212           // + 4*81
#define TSTRIDE 4248          // + 4*9  (multiple of 4)
#define NPT 4                 // nodes per thread in contraction kernel
#define BLK 256

// ------------------------------------------------------------- sort: count
__global__ __launch_bounds__(BLK) void count_kernel(
    const float* __restrict__ attrs, int N,
    int* __restrict__ elem, int* __restrict__ gcnt) {
  int n = blockIdx.x * BLK + threadIdx.x;
  if (n >= N) return;
  const float* a = attrs + n * NE;
  int e = 0;
#pragma unroll
  for (int j = 1; j < NE; ++j)
    if (a[j] > 0.5f) e = j;
  elem[n] = e;
  atomicAdd(&gcnt[e], 1);
}

// ------------------------------------------------------------ sort: prefix
__global__ void offs_kernel(const int* __restrict__ gcnt,
                            int* __restrict__ offs, int* __restrict__ cur) {
  if (threadIdx.x == 0) {
    int acc = 0;
    for (int k = 0; k < NE; ++k) { offs[k] = acc; cur[k] = acc; acc += gcnt[k]; }
    offs[NE] = acc;
  }
}

// ----------------------------------------------------------- sort: scatter
__global__ __launch_bounds__(BLK) void scatter_kernel(
    const int* __restrict__ elem, int N,
    int* __restrict__ cur, int* __restrict__ order) {
  int n = blockIdx.x * BLK + threadIdx.x;
  if (n >= N) return;
  int e = elem[n];
  int lane = threadIdx.x & 63;
#pragma unroll
  for (int k = 0; k < NE; ++k) {
    if (e == k) {
      unsigned long long m = __ballot(1);
      int cnt = __popcll(m);
      int leader = __ffsll((long long)m) - 1;
      int base = 0;
      if (lane == leader) base = atomicAdd(&cur[k], cnt);
      base = __shfl(base, leader);
      int rank = __popcll(m & ((1ull << lane) - 1ull));
      order[base + rank] = n;
    }
  }
}

// ------------------------------------------------- build U (x) w coefficient tables
__global__ __launch_bounds__(BLK) void table_kernel(
    const float* __restrict__ U3_0, const float* __restrict__ U2_0,
    const float* __restrict__ U1_0, const float* __restrict__ U3_1,
    const float* __restrict__ U2_1, const float* __restrict__ U1_1,
    const float* __restrict__ w3_0, const float* __restrict__ w2_0,
    const float* __restrict__ w1_0, const float* __restrict__ w3_1,
    const float* __restrict__ w2_1, const float* __restrict__ w1_1,
    float* __restrict__ table) {
  int b = blockIdx.x;              // e*CCH + c
  int e = b / CCH, c = b % CCH;
  float* T = table + (size_t)b * TSTRIDE;
  for (int idx = threadIdx.x; idx < TSTRIDE; idx += BLK) {
    float acc = 0.f;
    if (idx < T2_OFF) {            // T3[dd][u*9+v][w(pad 12)], dd=0 irrep0
      int dd = idx / 972, rem = idx % 972;
      int uv = rem / T3ROW, w = rem % T3ROW;
      if (w < 9) {
        int r = uv * 9 + w;        // u*81+v*9+w
        if (dd == 0) {
          for (int k = 0; k < 10; ++k)
            acc += U3_0[r * 10 + k] * w3_0[(e * 10 + k) * CCH + c];
        } else {
          int d = dd - 1;
          for (int k = 0; k < 12; ++k)
            acc += U3_1[(d * 729 + r) * 12 + k] * w3_1[(e * 12 + k) * CCH + c];
        }
      }
    } else if (idx < T1_OFF) {     // T2[dd][u*9+v]
      int i2 = idx - T2_OFF;
      int dd = i2 / 81, rem = i2 % 81;
      if (dd == 0) {
        for (int k = 0; k < 3; ++k)
          acc += U2_0[rem * 3 + k] * w2_0[(e * 3 + k) * CCH + c];
      } else {
        int d = dd - 1;
        for (int k = 0; k < 4; ++k)
          acc += U2_1[(d * 81 + rem) * 4 + k] * w2_1[(e * 4 + k) * CCH + c];
      }
    } else if (idx < TSTRIDE) {    // T1[dd][u]
      int i1 = idx - T1_OFF;
      int dd = i1 / 9, u = i1 % 9;
      if (dd == 0) acc = U1_0[u] * w1_0[e * CCH + c];
      else         acc = U1_1[(dd - 1) * 9 + u] * w1_1[e * CCH + c];
    }
    T[idx] = acc;
  }
}

// ------------------------------------------------------- symmetric contraction
__global__ __launch_bounds__(BLK, 4) void contract_kernel(
    const float* __restrict__ feats, const float* __restrict__ table,
    const int* __restrict__ order, const int* __restrict__ offs,
    float* __restrict__ tmp, int NPAD) {
  const int c = blockIdx.y, e = blockIdx.z;
  const int start = offs[e], end = offs[e + 1];
  const int base = start + blockIdx.x * (BLK * NPT);
  if (base >= end) return;                      // block-uniform early exit

  __shared__ float T[TSTRIDE];
  {
    const float4* src = (const float4*)(table + (size_t)(e * CCH + c) * TSTRIDE);
    float4* dst = (float4*)T;
    for (int i = threadIdx.x; i < TSTRIDE / 4; i += BLK) dst[i] = src[i];
  }
  __syncthreads();

  const int tid = threadIdx.x;
  float x[NPT][LDIM];
  int pp[NPT];
  int valid[NPT];
#pragma unroll
  for (int i = 0; i < NPT; ++i) {
    int p = base + i * BLK + tid;
    valid[i] = (p < end);
    pp[i] = valid[i] ? p : 0;
#pragma unroll
    for (int w = 0; w < LDIM; ++w) x[i][w] = 0.f;
    if (valid[i]) {
      int n = order[p];
      const float* xp = feats + ((size_t)n * CCH + c) * LDIM;
#pragma unroll
      for (int w = 0; w < LDIM; ++w) x[i][w] = xp[w];
    }
  }

#pragma unroll 1
  for (int dd = 0; dd < 4; ++dd) {
    const float* T3 = T + dd * 972;
    const float* T2 = T + T2_OFF + dd * 81;
    const float* T1 = T + T1_OFF + dd * 9;
    float accd[NPT];
#pragma unroll
    for (int i = 0; i < NPT; ++i) accd[i] = 0.f;
#pragma unroll
    for (int u = 0; u < 9; ++u) {                 // FULLY unrolled
      float t1 = T1[u];
      float accu[NPT];
#pragma unroll
      for (int i = 0; i < NPT; ++i) accu[i] = t1;
#pragma unroll
      for (int v = 0; v < 9; ++v) {               // FULLY unrolled
        float t2 = T2[u * 9 + v];
        const float4* row = (const float4*)(T3 + (u * 9 + v) * T3ROW);
        float4 r0 = row[0];
        float4 r1 = row[1];
        float t38 = T3[(u * 9 + v) * T3ROW + 8];
#pragma unroll
        for (int i = 0; i < NPT; ++i) {
          float a = fmaf(x[i][0], r0.x, t2);
          a = fmaf(x[i][1], r0.y, a);
          a = fmaf(x[i][2], r0.z, a);
          a = fmaf(x[i][3], r0.w, a);
          a = fmaf(x[i][4], r1.x, a);
          a = fmaf(x[i][5], r1.y, a);
          a = fmaf(x[i][6], r1.z, a);
          a = fmaf(x[i][7], r1.w, a);
          a = fmaf(x[i][8], t38, a);
          accu[i] = fmaf(a, x[i][v], accu[i]);    // v is compile-time
        }
      }
#pragma unroll
      for (int i = 0; i < NPT; ++i)
        accd[i] = fmaf(accu[i], x[i][u], accd[i]); // u is compile-time
    }
    float* o = tmp + (size_t)(dd * CCH + c) * NPAD;
#pragma unroll
    for (int i = 0; i < NPT; ++i)
      if (valid[i]) o[pp[i]] = accd[i];           // consecutive p -> coalesced
  }
}

// ------------------------------------------------------ o3.Linear + residual
__global__ __launch_bounds__(BLK) void linear_kernel(
    const float* __restrict__ tmp, const float* __restrict__ W0,
    const float* __restrict__ W1, const float* __restrict__ sc,
    const int* __restrict__ order, float* __restrict__ out, int N, int NPAD) {
  const int dd = blockIdx.y;                    // 0..3
  const int co = threadIdx.x & (CCH - 1);
  const int half = threadIdx.x >> 7;            // 0/1
  const int PT = 8;
  const int p0 = blockIdx.x * (PT * 2) + half * PT;
  if (p0 >= N) return;
  const float* W = (dd == 0) ? W0 : W1;
  const float* A = tmp + (size_t)(dd * CCH) * NPAD + p0;
  float acc[PT];
#pragma unroll
  for (int j = 0; j < PT; ++j) acc[j] = 0.f;
  for (int ci = 0; ci < CCH; ++ci) {
    float wv = W[ci * CCH + co];                // coalesced across lanes
    const float4* ap4 = (const float4*)(A + (size_t)ci * NPAD);
    float4 a0 = ap4[0], a1 = ap4[1];            // wave-uniform -> broadcast
    acc[0] = fmaf(a0.x, wv, acc[0]);
    acc[1] = fmaf(a0.y, wv, acc[1]);
    acc[2] = fmaf(a0.z, wv, acc[2]);
    acc[3] = fmaf(a0.w, wv, acc[3]);
    acc[4] = fmaf(a1.x, wv, acc[4]);
    acc[5] = fmaf(a1.y, wv, acc[5]);
    acc[6] = fmaf(a1.z, wv, acc[6]);
    acc[7] = fmaf(a1.w, wv, acc[7]);
  }
  const float s = 0.08838834764831843f;         // 1/sqrt(128)
#pragma unroll
  for (int j = 0; j < PT; ++j) {
    int p = p0 + j;
    if (p < N) {
      int n = order[p];
      int off = (dd == 0) ? co : (CCH + co * 3 + (dd - 1));
      size_t oi = (size_t)n * 512 + off;
      out[oi] = acc[j] * s + sc[oi];
    }
  }
}

// -------------------------------------------------------------------- launch
extern "C" void kernel_launch(void* const* d_in, const int* in_sizes, int n_in,
                              void* d_out, int out_size, void* d_ws, size_t ws_size,
                              hipStream_t stream) {
  const float* feats = (const float*)d_in[0];
  const float* attrs = (const float*)d_in[1];
  const float* sc    = (const float*)d_in[2];
  const float* U3_0  = (const float*)d_in[3];
  const float* U2_0  = (const float*)d_in[4];
  const float* U1_0  = (const float*)d_in[5];
  const float* w3_0  = (const float*)d_in[6];
  const float* w2_0  = (const float*)d_in[7];
  const float* w1_0  = (const float*)d_in[8];
  const float* U3_1  = (const float*)d_in[9];
  const float* U2_1  = (const float*)d_in[10];
  const float* U1_1  = (const float*)d_in[11];
  const float* w3_1  = (const float*)d_in[12];
  const float* w2_1  = (const float*)d_in[13];
  const float* w1_1  = (const float*)d_in[14];
  const float* W0    = (const float*)d_in[15];
  const float* W1    = (const float*)d_in[16];

  const int N = in_sizes[0] / (CCH * LDIM);     // 10000
  const int NPAD = ((N + 15) & ~15) + 16;

  // workspace (floats): tables | tmp[4*C][NPAD] | order[N] elem[N] offs[8] cur[8] gcnt[8]
  float* table = (float*)d_ws;
  float* tmp   = table + (size_t)NE * CCH * TSTRIDE;
  int*   order = (int*)(tmp + (size_t)4 * CCH * NPAD);
  int*   elem  = order + N;
  int*   offs  = elem + N;
  int*   cur   = offs + 8;
  int*   gcnt  = cur + 8;
  float* out   = (float*)d_out;

  hipMemsetAsync(gcnt, 0, NE * sizeof(int), stream);

  const int nblk = (N + BLK - 1) / BLK;
  count_kernel<<<dim3(nblk), dim3(BLK), 0, stream>>>(attrs, N, elem, gcnt);
  offs_kernel<<<dim3(1), dim3(64), 0, stream>>>(gcnt, offs, cur);
  scatter_kernel<<<dim3(nblk), dim3(BLK), 0, stream>>>(elem, N, cur, order);

  table_kernel<<<dim3(NE * CCH), dim3(BLK), 0, stream>>>(
      U3_0, U2_0, U1_0, U3_1, U2_1, U1_1,
      w3_0, w2_0, w1_0, w3_1, w2_1, w1_1, table);

  const int chunks = (N + BLK * NPT - 1) / (BLK * NPT);
  contract_kernel<<<dim3(chunks, CCH, NE), dim3(BLK), 0, stream>>>(
      feats, table, order, offs, tmp, NPAD);

  linear_kernel<<<dim3((N + 15) / 16, 4), dim3(BLK), 0, stream>>>(
      tmp, W0, W1, sc, order, out, N, NPAD);
}

// Round 4
// 410.748 us; speedup vs baseline: 13.3385x; 13.3385x over previous
//
#include <hip/hip_runtime.h>

// EquivariantProductBasisBlock (MACE symmetric contraction, corr=3) + o3.Linear
// N=10000 nodes, C=128 channels, L=9 (lmax=2), E=5 elements, fp32 throughout.
//
// R4 changes vs R3:
//  - R3's full u,v unroll (~3.6K-instr body) made the scheduler batch LDS
//    loads -> spill -> 12 GB scratch traffic. R2's rolled u,v made x[]
//    runtime-indexed -> demoted to scratch. R4: dd,u rolled (bounded ~430
//    instr body), v,w unrolled (compile-time x indices), x[u] via an 8-deep
//    cndmask select chain (no runtime reg-array index anywhere).
//  - Table rows repacked [w0..w8, t2, 0, 0] -> 2x b128 + 1x b64 per row.
//  - __launch_bounds__(256,3): VGPR cap ~170, est. use ~105, no spill.

#define CCH 128
#define LDIM 9
#define NE 5
// per (e,c) table: T3[dd][81 rows][12: w0..w8,t2,0,0] | T1[dd][9]
#define T1OFF 3888            // 4*81*12
#define TSTRIDE 3924          // + 4*9 (multiple of 4)
#define NPT 4                 // nodes per thread in contraction kernel
#define BLK 256

// ------------------------------------------------------------- sort: count
__global__ __launch_bounds__(BLK) void count_kernel(
    const float* __restrict__ attrs, int N,
    int* __restrict__ elem, int* __restrict__ gcnt) {
  int n = blockIdx.x * BLK + threadIdx.x;
  if (n >= N) return;
  const float* a = attrs + n * NE;
  int e = 0;
#pragma unroll
  for (int j = 1; j < NE; ++j)
    if (a[j] > 0.5f) e = j;
  elem[n] = e;
  atomicAdd(&gcnt[e], 1);
}

// ------------------------------------------------------------ sort: prefix
__global__ void offs_kernel(const int* __restrict__ gcnt,
                            int* __restrict__ offs, int* __restrict__ cur) {
  if (threadIdx.x == 0) {
    int acc = 0;
    for (int k = 0; k < NE; ++k) { offs[k] = acc; cur[k] = acc; acc += gcnt[k]; }
    offs[NE] = acc;
  }
}

// ----------------------------------------------------------- sort: scatter
__global__ __launch_bounds__(BLK) void scatter_kernel(
    const int* __restrict__ elem, int N,
    int* __restrict__ cur, int* __restrict__ order) {
  int n = blockIdx.x * BLK + threadIdx.x;
  if (n >= N) return;
  int e = elem[n];
  int lane = threadIdx.x & 63;
#pragma unroll
  for (int k = 0; k < NE; ++k) {
    if (e == k) {
      unsigned long long m = __ballot(1);
      int cnt = __popcll(m);
      int leader = __ffsll((long long)m) - 1;
      int base = 0;
      if (lane == leader) base = atomicAdd(&cur[k], cnt);
      base = __shfl(base, leader);
      int rank = __popcll(m & ((1ull << lane) - 1ull));
      order[base + rank] = n;
    }
  }
}

// ------------------------------------------------- build U (x) w coefficient tables
__global__ __launch_bounds__(BLK) void table_kernel(
    const float* __restrict__ U3_0, const float* __restrict__ U2_0,
    const float* __restrict__ U1_0, const float* __restrict__ U3_1,
    const float* __restrict__ U2_1, const float* __restrict__ U1_1,
    const float* __restrict__ w3_0, const float* __restrict__ w2_0,
    const float* __restrict__ w1_0, const float* __restrict__ w3_1,
    const float* __restrict__ w2_1, const float* __restrict__ w1_1,
    float* __restrict__ table) {
  int b = blockIdx.x;              // e*CCH + c
  int e = b / CCH, c = b % CCH;
  float* T = table + (size_t)b * TSTRIDE;
  for (int idx = threadIdx.x; idx < TSTRIDE; idx += BLK) {
    float acc = 0.f;
    if (idx < T1OFF) {             // T3 region: [dd][u*9+v][12]
      int dd = idx / 972, rem = idx % 972;
      int row = rem / 12, w = rem % 12;    // row = u*9+v
      if (w < 9) {                 // cubic coefficient
        int r = row * 9 + w;       // u*81+v*9+w
        if (dd == 0) {
          for (int k = 0; k < 10; ++k)
            acc += U3_0[r * 10 + k] * w3_0[(e * 10 + k) * CCH + c];
        } else {
          int d = dd - 1;
          for (int k = 0; k < 12; ++k)
            acc += U3_1[(d * 729 + r) * 12 + k] * w3_1[(e * 12 + k) * CCH + c];
        }
      } else if (w == 9) {         // quadratic coefficient t2[row]
        if (dd == 0) {
          for (int k = 0; k < 3; ++k)
            acc += U2_0[row * 3 + k] * w2_0[(e * 3 + k) * CCH + c];
        } else {
          int d = dd - 1;
          for (int k = 0; k < 4; ++k)
            acc += U2_1[(d * 81 + row) * 4 + k] * w2_1[(e * 4 + k) * CCH + c];
        }
      }                            // w==10,11: padding zeros
    } else {                       // T1[dd][u]
      int i1 = idx - T1OFF;
      int dd = i1 / 9, u = i1 % 9;
      if (dd == 0) acc = U1_0[u] * w1_0[e * CCH + c];
      else         acc = U1_1[(dd - 1) * 9 + u] * w1_1[e * CCH + c];
    }
    T[idx] = acc;
  }
}

// ------------------------------------------------------- symmetric contraction
__global__ __launch_bounds__(BLK, 3) void contract_kernel(
    const float* __restrict__ feats, const float* __restrict__ table,
    const int* __restrict__ order, const int* __restrict__ offs,
    float* __restrict__ tmp, int NPAD) {
  const int c = blockIdx.y, e = blockIdx.z;
  const int start = offs[e], end = offs[e + 1];
  const int base = start + blockIdx.x * (BLK * NPT);
  if (base >= end) return;                      // block-uniform early exit

  __shared__ float T[TSTRIDE];
  {
    const float4* src = (const float4*)(table + (size_t)(e * CCH + c) * TSTRIDE);
    float4* dst = (float4*)T;
    for (int i = threadIdx.x; i < TSTRIDE / 4; i += BLK) dst[i] = src[i];
  }
  __syncthreads();

  const int tid = threadIdx.x;
  float x[NPT][LDIM];
  int pp[NPT];
  bool valid[NPT];
#pragma unroll
  for (int i = 0; i < NPT; ++i) {
    int p = base + i * BLK + tid;
    valid[i] = (p < end);
    int p2 = valid[i] ? p : (end - 1);          // clamp: stay in-bounds
    pp[i] = p;
    int n = order[p2];
    const float* xp = feats + ((size_t)n * CCH + c) * LDIM;
#pragma unroll
    for (int w = 0; w < LDIM; ++w) x[i][w] = xp[w];
  }

#pragma unroll 1
  for (int dd = 0; dd < 4; ++dd) {
    const float* T3d = T + dd * 972;
    const float* T1d = T + T1OFF + dd * 9;
    float accd[NPT];
#pragma unroll
    for (int i = 0; i < NPT; ++i) accd[i] = 0.f;
#pragma unroll 1
    for (int u = 0; u < 9; ++u) {
      // xu[i] = x[i][u] via select chain (u is runtime; structure compile-time)
      float xu[NPT];
#pragma unroll
      for (int i = 0; i < NPT; ++i) {
        float t = x[i][0];
#pragma unroll
        for (int k = 1; k < 9; ++k) t = (u == k) ? x[i][k] : t;
        xu[i] = t;
      }
      float t1 = T1d[u];
      float accu[NPT];
#pragma unroll
      for (int i = 0; i < NPT; ++i) accu[i] = t1;
      const float* Trow = T3d + u * 108;        // 9 rows * 12 floats
#pragma unroll
      for (int v = 0; v < 9; ++v) {
        const float4* r4 = (const float4*)(Trow + v * 12);
        float4 r0 = r4[0];
        float4 r1 = r4[1];
        float2 r2 = *(const float2*)(Trow + v * 12 + 8);  // {w8, t2}
#pragma unroll
        for (int i = 0; i < NPT; ++i) {
          float a = fmaf(x[i][0], r0.x, r2.y);
          a = fmaf(x[i][1], r0.y, a);
          a = fmaf(x[i][2], r0.z, a);
          a = fmaf(x[i][3], r0.w, a);
          a = fmaf(x[i][4], r1.x, a);
          a = fmaf(x[i][5], r1.y, a);
          a = fmaf(x[i][6], r1.z, a);
          a = fmaf(x[i][7], r1.w, a);
          a = fmaf(x[i][8], r2.x, a);
          accu[i] = fmaf(a, x[i][v], accu[i]);  // v compile-time
        }
      }
#pragma unroll
      for (int i = 0; i < NPT; ++i) accd[i] = fmaf(accu[i], xu[i], accd[i]);
    }
    float* o = tmp + (size_t)(dd * CCH + c) * NPAD;
#pragma unroll
    for (int i = 0; i < NPT; ++i)
      if (valid[i]) o[pp[i]] = accd[i];         // consecutive p -> coalesced
  }
}

// ------------------------------------------------------ o3.Linear + residual
__global__ __launch_bounds__(BLK) void linear_kernel(
    const float* __restrict__ tmp, const float* __restrict__ W0,
    const float* __restrict__ W1, const float* __restrict__ sc,
    const int* __restrict__ order, float* __restrict__ out, int N, int NPAD) {
  const int dd = blockIdx.y;                    // 0..3
  const int co = threadIdx.x & (CCH - 1);
  const int half = threadIdx.x >> 7;            // 0/1
  const int PT = 8;
  const int p0 = blockIdx.x * (PT * 2) + half * PT;
  if (p0 >= N) return;
  const float* W = (dd == 0) ? W0 : W1;
  const float* A = tmp + (size_t)(dd * CCH) * NPAD + p0;
  float acc[PT];
#pragma unroll
  for (int j = 0; j < PT; ++j) acc[j] = 0.f;
#pragma unroll 4
  for (int ci = 0; ci < CCH; ++ci) {
    float wv = W[ci * CCH + co];                // coalesced across lanes
    const float4* ap4 = (const float4*)(A + (size_t)ci * NPAD);
    float4 a0 = ap4[0], a1 = ap4[1];            // wave-uniform -> broadcast
    acc[0] = fmaf(a0.x, wv, acc[0]);
    acc[1] = fmaf(a0.y, wv, acc[1]);
    acc[2] = fmaf(a0.z, wv, acc[2]);
    acc[3] = fmaf(a0.w, wv, acc[3]);
    acc[4] = fmaf(a1.x, wv, acc[4]);
    acc[5] = fmaf(a1.y, wv, acc[5]);
    acc[6] = fmaf(a1.z, wv, acc[6]);
    acc[7] = fmaf(a1.w, wv, acc[7]);
  }
  const float s = 0.08838834764831843f;         // 1/sqrt(128)
#pragma unroll
  for (int j = 0; j < PT; ++j) {
    int p = p0 + j;
    if (p < N) {
      int n = order[p];
      int off = (dd == 0) ? co : (CCH + co * 3 + (dd - 1));
      size_t oi = (size_t)n * 512 + off;
      out[oi] = acc[j] * s + sc[oi];
    }
  }
}

// -------------------------------------------------------------------- launch
extern "C" void kernel_launch(void* const* d_in, const int* in_sizes, int n_in,
                              void* d_out, int out_size, void* d_ws, size_t ws_size,
                              hipStream_t stream) {
  const float* feats = (const float*)d_in[0];
  const float* attrs = (const float*)d_in[1];
  const float* sc    = (const float*)d_in[2];
  const float* U3_0  = (const float*)d_in[3];
  const float* U2_0  = (const float*)d_in[4];
  const float* U1_0  = (const float*)d_in[5];
  const float* w3_0  = (const float*)d_in[6];
  const float* w2_0  = (const float*)d_in[7];
  const float* w1_0  = (const float*)d_in[8];
  const float* U3_1  = (const float*)d_in[9];
  const float* U2_1  = (const float*)d_in[10];
  const float* U1_1  = (const float*)d_in[11];
  const float* w3_1  = (const float*)d_in[12];
  const float* w2_1  = (const float*)d_in[13];
  const float* w1_1  = (const float*)d_in[14];
  const float* W0    = (const float*)d_in[15];
  const float* W1    = (const float*)d_in[16];

  const int N = in_sizes[0] / (CCH * LDIM);     // 10000
  const int NPAD = ((N + 15) & ~15) + 16;

  // workspace (floats): tables | tmp[4*C][NPAD] | order[N] elem[N] offs[8] cur[8] gcnt[8]
  float* table = (float*)d_ws;
  float* tmp   = table + (size_t)NE * CCH * TSTRIDE;
  int*   order = (int*)(tmp + (size_t)4 * CCH * NPAD);
  int*   elem  = order + N;
  int*   offs  = elem + N;
  int*   cur   = offs + 8;
  int*   gcnt  = cur + 8;
  float* out   = (float*)d_out;

  hipMemsetAsync(gcnt, 0, NE * sizeof(int), stream);

  const int nblk = (N + BLK - 1) / BLK;
  count_kernel<<<dim3(nblk), dim3(BLK), 0, stream>>>(attrs, N, elem, gcnt);
  offs_kernel<<<dim3(1), dim3(64), 0, stream>>>(gcnt, offs, cur);
  scatter_kernel<<<dim3(nblk), dim3(BLK), 0, stream>>>(elem, N, cur, order);

  table_kernel<<<dim3(NE * CCH), dim3(BLK), 0, stream>>>(
      U3_0, U2_0, U1_0, U3_1, U2_1, U1_1,
      w3_0, w2_0, w1_0, w3_1, w2_1, w1_1, table);

  const int chunks = (N + BLK * NPT - 1) / (BLK * NPT);
  contract_kernel<<<dim3(chunks, CCH, NE), dim3(BLK), 0, stream>>>(
      feats, table, order, offs, tmp, NPAD);

  linear_kernel<<<dim3((N + 15) / 16, 4), dim3(BLK), 0, stream>>>(
      tmp, W0, W1, sc, order, out, N, NPAD);
}

// Round 5
// 372.648 us; speedup vs baseline: 14.7022x; 1.1022x over previous
//
#include <hip/hip_runtime.h>

// EquivariantProductBasisBlock (MACE symmetric contraction, corr=3) + o3.Linear
// N=10000 nodes, C=128 channels, L=9 (lmax=2), E=5 elements, fp32 throughout.
//
// R5 changes vs R4 (contract_kernel untouched — verified at 131 us, no spill):
//  - table_kernel: U3 global reads had 48B inter-lane stride (~48 lines per
//    wave-load). Now stages each dd's U-slice (<=35 KB) into LDS with
//    coalesced loads; w-weights are block-uniform scalar loads.
//  - count_kernel: 10000 same-address atomics -> ballot-aggregated (5/wave).
//  - linear_kernel: PT 8->16 (16 FMA per ~5 loads, half the blocks).

#define CCH 128
#define LDIM 9
#define NE 5
// per (e,c) table: T3[dd][81 rows][12: w0..w8,t2,0,0] | T1[dd][9]
#define T1OFF 3888            // 4*81*12
#define TSTRIDE 3924          // + 4*9 (multiple of 4)
#define NPT 4                 // nodes per thread in contraction kernel
#define BLK 256
#define U3LDS 8748            // max staged U3 slice (729*12 floats)

// ------------------------------------------------------------- sort: count
__global__ __launch_bounds__(BLK) void count_kernel(
    const float* __restrict__ attrs, int N,
    int* __restrict__ elem, int* __restrict__ gcnt) {
  int n = blockIdx.x * BLK + threadIdx.x;
  if (n >= N) return;
  const float* a = attrs + n * NE;
  int e = 0;
#pragma unroll
  for (int j = 1; j < NE; ++j)
    if (a[j] > 0.5f) e = j;
  elem[n] = e;
  int lane = threadIdx.x & 63;
#pragma unroll
  for (int k = 0; k < NE; ++k) {
    unsigned long long m = __ballot(e == k);
    if (m) {
      int leader = __ffsll((long long)m) - 1;
      if (lane == leader) atomicAdd(&gcnt[k], __popcll(m));
    }
  }
}

// ------------------------------------------------------------ sort: prefix
__global__ void offs_kernel(const int* __restrict__ gcnt,
                            int* __restrict__ offs, int* __restrict__ cur) {
  if (threadIdx.x == 0) {
    int acc = 0;
    for (int k = 0; k < NE; ++k) { offs[k] = acc; cur[k] = acc; acc += gcnt[k]; }
    offs[NE] = acc;
  }
}

// ----------------------------------------------------------- sort: scatter
__global__ __launch_bounds__(BLK) void scatter_kernel(
    const int* __restrict__ elem, int N,
    int* __restrict__ cur, int* __restrict__ order) {
  int n = blockIdx.x * BLK + threadIdx.x;
  if (n >= N) return;
  int e = elem[n];
  int lane = threadIdx.x & 63;
#pragma unroll
  for (int k = 0; k < NE; ++k) {
    if (e == k) {
      unsigned long long m = __ballot(1);
      int cnt = __popcll(m);
      int leader = __ffsll((long long)m) - 1;
      int base = 0;
      if (lane == leader) base = atomicAdd(&cur[k], cnt);
      base = __shfl(base, leader);
      int rank = __popcll(m & ((1ull << lane) - 1ull));
      order[base + rank] = n;
    }
  }
}

// --------------------------------- build U (x) w coefficient tables (LDS-staged)
__global__ __launch_bounds__(BLK) void table_kernel(
    const float* __restrict__ U3_0, const float* __restrict__ U2_0,
    const float* __restrict__ U1_0, const float* __restrict__ U3_1,
    const float* __restrict__ U2_1, const float* __restrict__ U1_1,
    const float* __restrict__ w3_0, const float* __restrict__ w2_0,
    const float* __restrict__ w1_0, const float* __restrict__ w3_1,
    const float* __restrict__ w2_1, const float* __restrict__ w1_1,
    float* __restrict__ table) {
  int b = blockIdx.x;              // e*CCH + c
  int e = b / CCH, c = b % CCH;
  float* T = table + (size_t)b * TSTRIDE;
  __shared__ float Us[U3LDS + 324 + 12];   // U3 slice | U2 slice | U1 slice

  // ---- dd = 0 (irrep l=0): U3_0[729][10], U2_0[81][3], U1_0[9]
  for (int i = threadIdx.x; i < 7290; i += BLK) Us[i] = U3_0[i];
  for (int i = threadIdx.x; i < 243; i += BLK)  Us[U3LDS + i] = U2_0[i];
  if (threadIdx.x < 9) Us[U3LDS + 324 + threadIdx.x] = U1_0[threadIdx.x];
  float w3a[10], w2a[3];
#pragma unroll
  for (int k = 0; k < 10; ++k) w3a[k] = w3_0[(e * 10 + k) * CCH + c];
#pragma unroll
  for (int k = 0; k < 3; ++k)  w2a[k] = w2_0[(e * 3 + k) * CCH + c];
  __syncthreads();
  for (int idx = threadIdx.x; idx < 972; idx += BLK) {
    int row = idx / 12, w = idx % 12;      // row = u*9+v
    float acc = 0.f;
    if (w < 9) {
      int r = row * 9 + w;
#pragma unroll
      for (int k = 0; k < 10; ++k) acc += Us[r * 10 + k] * w3a[k];
    } else if (w == 9) {
#pragma unroll
      for (int k = 0; k < 3; ++k) acc += Us[U3LDS + row * 3 + k] * w2a[k];
    }
    T[idx] = acc;                          // coalesced
  }
  if (threadIdx.x < 9)
    T[T1OFF + threadIdx.x] = Us[U3LDS + 324 + threadIdx.x] * w1_0[e * CCH + c];

  // ---- dd = 1..3 (irrep l=1): U3_1[d][729][12], U2_1[d][81][4], U1_1[d][9]
#pragma unroll 1
  for (int d = 0; d < 3; ++d) {
    __syncthreads();                       // all reads of Us done
    for (int i = threadIdx.x; i < 8748; i += BLK) Us[i] = U3_1[d * 8748 + i];
    for (int i = threadIdx.x; i < 324; i += BLK)  Us[U3LDS + i] = U2_1[d * 324 + i];
    if (threadIdx.x < 9) Us[U3LDS + 324 + threadIdx.x] = U1_1[d * 9 + threadIdx.x];
    float w3b[12], w2b[4];
#pragma unroll
    for (int k = 0; k < 12; ++k) w3b[k] = w3_1[(e * 12 + k) * CCH + c];
#pragma unroll
    for (int k = 0; k < 4; ++k)  w2b[k] = w2_1[(e * 4 + k) * CCH + c];
    __syncthreads();
    float* Td = T + (d + 1) * 972;
    for (int idx = threadIdx.x; idx < 972; idx += BLK) {
      int row = idx / 12, w = idx % 12;
      float acc = 0.f;
      if (w < 9) {
        int r = row * 9 + w;
#pragma unroll
        for (int k = 0; k < 12; ++k) acc += Us[r * 12 + k] * w3b[k];
      } else if (w == 9) {
#pragma unroll
        for (int k = 0; k < 4; ++k) acc += Us[U3LDS + row * 4 + k] * w2b[k];
      }
      Td[idx] = acc;
    }
    if (threadIdx.x < 9)
      T[T1OFF + (d + 1) * 9 + threadIdx.x] =
          Us[U3LDS + 324 + threadIdx.x] * w1_1[e * CCH + c];
  }
}

// ------------------------------------------------------- symmetric contraction
__global__ __launch_bounds__(BLK, 3) void contract_kernel(
    const float* __restrict__ feats, const float* __restrict__ table,
    const int* __restrict__ order, const int* __restrict__ offs,
    float* __restrict__ tmp, int NPAD) {
  const int c = blockIdx.y, e = blockIdx.z;
  const int start = offs[e], end = offs[e + 1];
  const int base = start + blockIdx.x * (BLK * NPT);
  if (base >= end) return;                      // block-uniform early exit

  __shared__ float T[TSTRIDE];
  {
    const float4* src = (const float4*)(table + (size_t)(e * CCH + c) * TSTRIDE);
    float4* dst = (float4*)T;
    for (int i = threadIdx.x; i < TSTRIDE / 4; i += BLK) dst[i] = src[i];
  }
  __syncthreads();

  const int tid = threadIdx.x;
  float x[NPT][LDIM];
  int pp[NPT];
  bool valid[NPT];
#pragma unroll
  for (int i = 0; i < NPT; ++i) {
    int p = base + i * BLK + tid;
    valid[i] = (p < end);
    int p2 = valid[i] ? p : (end - 1);          // clamp: stay in-bounds
    pp[i] = p;
    int n = order[p2];
    const float* xp = feats + ((size_t)n * CCH + c) * LDIM;
#pragma unroll
    for (int w = 0; w < LDIM; ++w) x[i][w] = xp[w];
  }

#pragma unroll 1
  for (int dd = 0; dd < 4; ++dd) {
    const float* T3d = T + dd * 972;
    const float* T1d = T + T1OFF + dd * 9;
    float accd[NPT];
#pragma unroll
    for (int i = 0; i < NPT; ++i) accd[i] = 0.f;
#pragma unroll 1
    for (int u = 0; u < 9; ++u) {
      // xu[i] = x[i][u] via select chain (u is runtime; structure compile-time)
      float xu[NPT];
#pragma unroll
      for (int i = 0; i < NPT; ++i) {
        float t = x[i][0];
#pragma unroll
        for (int k = 1; k < 9; ++k) t = (u == k) ? x[i][k] : t;
        xu[i] = t;
      }
      float t1 = T1d[u];
      float accu[NPT];
#pragma unroll
      for (int i = 0; i < NPT; ++i) accu[i] = t1;
      const float* Trow = T3d + u * 108;        // 9 rows * 12 floats
#pragma unroll
      for (int v = 0; v < 9; ++v) {
        const float4* r4 = (const float4*)(Trow + v * 12);
        float4 r0 = r4[0];
        float4 r1 = r4[1];
        float2 r2 = *(const float2*)(Trow + v * 12 + 8);  // {w8, t2}
#pragma unroll
        for (int i = 0; i < NPT; ++i) {
          float a = fmaf(x[i][0], r0.x, r2.y);
          a = fmaf(x[i][1], r0.y, a);
          a = fmaf(x[i][2], r0.z, a);
          a = fmaf(x[i][3], r0.w, a);
          a = fmaf(x[i][4], r1.x, a);
          a = fmaf(x[i][5], r1.y, a);
          a = fmaf(x[i][6], r1.z, a);
          a = fmaf(x[i][7], r1.w, a);
          a = fmaf(x[i][8], r2.x, a);
          accu[i] = fmaf(a, x[i][v], accu[i]);  // v compile-time
        }
      }
#pragma unroll
      for (int i = 0; i < NPT; ++i) accd[i] = fmaf(accu[i], xu[i], accd[i]);
    }
    float* o = tmp + (size_t)(dd * CCH + c) * NPAD;
#pragma unroll
    for (int i = 0; i < NPT; ++i)
      if (valid[i]) o[pp[i]] = accd[i];         // consecutive p -> coalesced
  }
}

// ------------------------------------------------------ o3.Linear + residual
#define LPT 16
__global__ __launch_bounds__(BLK) void linear_kernel(
    const float* __restrict__ tmp, const float* __restrict__ W0,
    const float* __restrict__ W1, const float* __restrict__ sc,
    const int* __restrict__ order, float* __restrict__ out, int N, int NPAD) {
  const int dd = blockIdx.y;                    // 0..3
  const int co = threadIdx.x & (CCH - 1);
  const int half = threadIdx.x >> 7;            // 0/1
  const int p0 = blockIdx.x * (LPT * 2) + half * LPT;
  if (p0 >= N) return;
  const float* W = (dd == 0) ? W0 : W1;
  const float* A = tmp + (size_t)(dd * CCH) * NPAD + p0;
  float acc[LPT];
#pragma unroll
  for (int j = 0; j < LPT; ++j) acc[j] = 0.f;
#pragma unroll 2
  for (int ci = 0; ci < CCH; ++ci) {
    float wv = W[ci * CCH + co];                // coalesced across lanes
    const float4* ap4 = (const float4*)(A + (size_t)ci * NPAD);
    float4 a0 = ap4[0], a1 = ap4[1], a2 = ap4[2], a3 = ap4[3];  // wave-uniform
    acc[0]  = fmaf(a0.x, wv, acc[0]);
    acc[1]  = fmaf(a0.y, wv, acc[1]);
    acc[2]  = fmaf(a0.z, wv, acc[2]);
    acc[3]  = fmaf(a0.w, wv, acc[3]);
    acc[4]  = fmaf(a1.x, wv, acc[4]);
    acc[5]  = fmaf(a1.y, wv, acc[5]);
    acc[6]  = fmaf(a1.z, wv, acc[6]);
    acc[7]  = fmaf(a1.w, wv, acc[7]);
    acc[8]  = fmaf(a2.x, wv, acc[8]);
    acc[9]  = fmaf(a2.y, wv, acc[9]);
    acc[10] = fmaf(a2.z, wv, acc[10]);
    acc[11] = fmaf(a2.w, wv, acc[11]);
    acc[12] = fmaf(a3.x, wv, acc[12]);
    acc[13] = fmaf(a3.y, wv, acc[13]);
    acc[14] = fmaf(a3.z, wv, acc[14]);
    acc[15] = fmaf(a3.w, wv, acc[15]);
  }
  const float s = 0.08838834764831843f;         // 1/sqrt(128)
#pragma unroll
  for (int j = 0; j < LPT; ++j) {
    int p = p0 + j;
    if (p < N) {
      int n = order[p];
      int off = (dd == 0) ? co : (CCH + co * 3 + (dd - 1));
      size_t oi = (size_t)n * 512 + off;
      out[oi] = acc[j] * s + sc[oi];
    }
  }
}

// -------------------------------------------------------------------- launch
extern "C" void kernel_launch(void* const* d_in, const int* in_sizes, int n_in,
                              void* d_out, int out_size, void* d_ws, size_t ws_size,
                              hipStream_t stream) {
  const float* feats = (const float*)d_in[0];
  const float* attrs = (const float*)d_in[1];
  const float* sc    = (const float*)d_in[2];
  const float* U3_0  = (const float*)d_in[3];
  const float* U2_0  = (const float*)d_in[4];
  const float* U1_0  = (const float*)d_in[5];
  const float* w3_0  = (const float*)d_in[6];
  const float* w2_0  = (const float*)d_in[7];
  const float* w1_0  = (const float*)d_in[8];
  const float* U3_1  = (const float*)d_in[9];
  const float* U2_1  = (const float*)d_in[10];
  const float* U1_1  = (const float*)d_in[11];
  const float* w3_1  = (const float*)d_in[12];
  const float* w2_1  = (const float*)d_in[13];
  const float* w1_1  = (const float*)d_in[14];
  const float* W0    = (const float*)d_in[15];
  const float* W1    = (const float*)d_in[16];

  const int N = in_sizes[0] / (CCH * LDIM);     // 10000
  const int NPAD = ((N + 15) & ~15) + 16;

  // workspace (floats): tables | tmp[4*C][NPAD] | order[N] elem[N] offs[8] cur[8] gcnt[8]
  float* table = (float*)d_ws;
  float* tmp   = table + (size_t)NE * CCH * TSTRIDE;
  int*   order = (int*)(tmp + (size_t)4 * CCH * NPAD);
  int*   elem  = order + N;
  int*   offs  = elem + N;
  int*   cur   = offs + 8;
  int*   gcnt  = cur + 8;
  float* out   = (float*)d_out;

  hipMemsetAsync(gcnt, 0, NE * sizeof(int), stream);

  const int nblk = (N + BLK - 1) / BLK;
  count_kernel<<<dim3(nblk), dim3(BLK), 0, stream>>>(attrs, N, elem, gcnt);
  offs_kernel<<<dim3(1), dim3(64), 0, stream>>>(gcnt, offs, cur);
  scatter_kernel<<<dim3(nblk), dim3(BLK), 0, stream>>>(elem, N, cur, order);

  table_kernel<<<dim3(NE * CCH), dim3(BLK), 0, stream>>>(
      U3_0, U2_0, U1_0, U3_1, U2_1, U1_1,
      w3_0, w2_0, w1_0, w3_1, w2_1, w1_1, table);

  const int chunks = (N + BLK * NPT - 1) / (BLK * NPT);
  contract_kernel<<<dim3(chunks, CCH, NE), dim3(BLK), 0, stream>>>(
      feats, table, order, offs, tmp, NPAD);

  linear_kernel<<<dim3((N + LPT * 2 - 1) / (LPT * 2), 4), dim3(BLK), 0, stream>>>(
      tmp, W0, W1, sc, order, out, N, NPAD);
}